// Round 1
// baseline (344.709 us; speedup 1.0000x reference)
//
#include <hip/hip_runtime.h>
#include <hip/hip_bf16.h>
#include <cstdint>
#include <cstddef>

typedef __bf16 bf16;
typedef __attribute__((ext_vector_type(8))) __bf16 bf16x8;
typedef __attribute__((ext_vector_type(4))) float f32x4;

static_assert(sizeof(bf16x8) == 16, "bf16x8 must be 16B");

#define NTASK 34
#define B_TOT 16384

__device__ __forceinline__ f32x4 mfma16(bf16x8 a, bf16x8 b, f32x4 c) {
  return __builtin_amdgcn_mfma_f32_16x16x32_bf16(a, b, c, 0, 0, 0);
}

__device__ __forceinline__ void gload_lds16(const void* g, void* l) {
  __builtin_amdgcn_global_load_lds((__attribute__((address_space(1))) void*)g,
                                   (__attribute__((address_space(3))) void*)l,
                                   16, 0, 0);
}

// ---------------- prep kernels ----------------

// Weights -> bf16 MFMA-B-fragment order:
// dst[(((n*ksteps + ks)*8 + ct)*64 + l)*8 + j] = W[n][k][col],
//   k = ks*32 + (l>>4)*8 + j, col = ct*16 + (l&15)
__global__ void prep_w(const float* __restrict__ src, bf16* __restrict__ dst,
                       int ksteps, int per_n, int total) {
  int idx = blockIdx.x * 256 + threadIdx.x;
  if (idx >= total) return;
  int n = idx / per_n;
  int r = idx - n * per_n;
  int ks = r >> 9;
  int ct = (r >> 6) & 7;
  int l = r & 63;
  int k0 = ks * 32 + ((l >> 4) << 3);
  int col = ct * 16 + (l & 15);
  const float* s = src + ((size_t)n * (ksteps * 32) + k0) * 128 + col;
  bf16x8 v;
#pragma unroll
  for (int j = 0; j < 8; ++j) v[j] = (bf16)s[(size_t)j * 128];
  *(bf16x8*)(dst + (size_t)idx * 8) = v;
}

// state -> bf16 A-fragment order:
// dst[((strip*8 + ks)*64 + l)*8 + j] = state[strip*16 + (l&15)][ks*32 + (l>>4)*8 + j]
__global__ void prep_state_frags(const float* __restrict__ state, bf16* __restrict__ dst) {
  int idx = blockIdx.x * 256 + threadIdx.x;   // 524288 total
  int strip = idx >> 9;
  int r = idx & 511;
  int ks = r >> 6;
  int l = r & 63;
  int b = strip * 16 + (l & 15);
  int k0 = ks * 32 + ((l >> 4) << 3);
  const float* s = state + (size_t)b * 256 + k0;
  bf16x8 v;
#pragma unroll
  for (int j = 0; j < 8; ++j) v[j] = (bf16)s[j];
  *(bf16x8*)(dst + (size_t)idx * 8) = v;
}

// copy raw f32 state into rep_vec[:, 0:256]
__global__ void prep_rep(const float* __restrict__ state, float* __restrict__ out_rep) {
  int i = blockIdx.x * 256 + threadIdx.x;     // exactly B*256 threads
  out_rep[(size_t)(i >> 8) * 384 + (i & 255)] = state[i];
}

// normalized lang embeddings (f32)
__global__ void prep_langn(const float* __restrict__ lang, float* __restrict__ out) {
  __shared__ float red[2];
  int n = blockIdx.x;
  int t = threadIdx.x;                         // 128 threads
  float v = lang[(size_t)n * 128 + t];
  float ss = v * v;
#pragma unroll
  for (int m = 1; m < 64; m <<= 1) ss += __shfl_xor(ss, m);
  if ((t & 63) == 0) red[t >> 6] = ss;
  __syncthreads();
  float s = red[0] + red[1];
  float sc = 1.0f / fmaxf(sqrtf(s), 1e-8f);
  out[(size_t)n * 128 + t] = v * sc;
}

// softmax(prior) -> bf16 [B][34]
__global__ void prep_pprior(const float* __restrict__ prior, bf16* __restrict__ pp) {
  int row = blockIdx.x * 4 + (threadIdx.x >> 6);
  int lane = threadIdx.x & 63;
  float v = (lane < NTASK) ? prior[(size_t)row * NTASK + lane] : -INFINITY;
  float m = v;
#pragma unroll
  for (int mm = 1; mm < 64; mm <<= 1) m = fmaxf(m, __shfl_xor(m, mm));
  float e = (lane < NTASK) ? expf(v - m) : 0.0f;
  float s = e;
#pragma unroll
  for (int mm = 1; mm < 64; mm <<= 1) s += __shfl_xor(s, mm);
  if (lane < NTASK) pp[(size_t)row * NTASK + lane] = (bf16)(e / s);
}

// ---------------- main fused kernel ----------------

__device__ __forceinline__ const bf16* chunk_src(int g, const bf16* w1f,
                                                 const bf16* w2f, const bf16* w3f) {
  int n = g >> 4, ph = g & 15;
  if (ph < 8) return w1f + (size_t)(n * 8 + ph) * 4096;
  if (ph < 12) return w2f + (size_t)(n * 4 + (ph - 8)) * 4096;
  return w3f + (size_t)(n * 4 + (ph - 12)) * 4096;
}

__global__ void __launch_bounds__(512, 2)
main_kernel(const int* __restrict__ task_id,
            const float* __restrict__ b1, const float* __restrict__ b2,
            const float* __restrict__ b3,
            const bf16* __restrict__ w1f, const bf16* __restrict__ w2f,
            const bf16* __restrict__ w3f, const bf16* __restrict__ sf,
            const float* __restrict__ langn, const bf16* __restrict__ pp,
            float* __restrict__ out_rep, float* __restrict__ out_ltp,
            float* __restrict__ out_tgt, float* __restrict__ out_lat) {
  __shared__ __align__(16) bf16 sh_w[2][4096];        // weight chunk double buffer
  __shared__ __align__(16) bf16 sh_h1[4][16][136];    // padded: 136*2B = 272B row stride
  __shared__ __align__(16) bf16 sh_h2[4][16][136];
  __shared__ float sh_cs[64 * NTASK];
  __shared__ bf16 sh_pp[64 * NTASK];
  __shared__ float sh_norm2[64];
  __shared__ int sh_tid[64];

  const int tid = threadIdx.x;
  const int l = tid & 63;
  const int w = tid >> 6;       // wave 0..7
  const int sidx = w >> 1;      // strip 0..3 (16 rows each)
  const int hf = w & 1;         // column half
  const int g4 = l >> 4;
  const int r16 = l & 15;
  const int blk = blockIdx.x;
  const int row0 = blk * 64;
  const int rloc = sidx * 16 + g4 * 4;  // +j = local row

  // stage chunk 0 (n=0, W1 ks=0)
  gload_lds16(w1f + (size_t)tid * 8, &sh_w[0][tid * 8]);

  if (tid < 64) sh_tid[tid] = task_id[row0 + tid];
  for (int i = tid; i < 64 * NTASK; i += 512) {
    sh_pp[i] = pp[(size_t)row0 * NTASK + i];
    sh_cs[i] = 0.0f;
  }

  // state A-fragments in registers (reused for all 34 tasks)
  bf16x8 sfrag[8];
  {
    const bf16* sp = sf + ((size_t)(blk * 4 + sidx) * 8 * 64 + l) * 8;
#pragma unroll
    for (int ks = 0; ks < 8; ++ks) sfrag[ks] = *(const bf16x8*)(sp + (size_t)ks * 512);
  }
  __syncthreads();   // chunk0 + sh_tid/sh_pp ready

  // per-lane normalized-lang fragment (f32), gathered once
  f32x4 lgn[4];
#pragma unroll
  for (int t = 0; t < 4; ++t) {
#pragma unroll
    for (int j = 0; j < 4; ++j)
      lgn[t][j] = langn[(size_t)sh_tid[rloc + j] * 128 + (hf * 64 + t * 16 + r16)];
  }
  const f32x4 fz = {0.f, 0.f, 0.f, 0.f};
  f32x4 lat[4] = {fz, fz, fz, fz};

  int g = 0;
  for (int n = 0; n < NTASK; ++n) {
    f32x4 acc[4] = {fz, fz, fz, fz};
    // ---- GEMM1: state[64x256] x W1[256x128], phases 0..7
#pragma unroll
    for (int ks = 0; ks < 8; ++ks) {
      if (g + 1 < NTASK * 16)
        gload_lds16(chunk_src(g + 1, w1f, w2f, w3f) + (size_t)tid * 8,
                    &sh_w[(g + 1) & 1][tid * 8]);
      const bf16* wb = &sh_w[g & 1][0];
#pragma unroll
      for (int t = 0; t < 4; ++t) {
        bf16x8 bfr = *(const bf16x8*)(wb + ((hf * 4 + t) * 64 + l) * 8);
        acc[t] = mfma16(sfrag[ks], bfr, acc[t]);
      }
      if (ks == 7) {
#pragma unroll
        for (int t = 0; t < 4; ++t) {
          float bb = b1[n * 128 + hf * 64 + t * 16 + r16];
#pragma unroll
          for (int j = 0; j < 4; ++j) {
            float v = fmaxf(acc[t][j] + bb, 0.0f);
            sh_h1[sidx][g4 * 4 + j][hf * 64 + t * 16 + r16] = (bf16)v;
          }
        }
      }
      __syncthreads();
      ++g;
    }
    // ---- GEMM2: h1[64x128] x W2[128x128], phases 8..11
#pragma unroll
    for (int t = 0; t < 4; ++t) acc[t] = fz;
#pragma unroll
    for (int ks = 0; ks < 4; ++ks) {
      if (g + 1 < NTASK * 16)
        gload_lds16(chunk_src(g + 1, w1f, w2f, w3f) + (size_t)tid * 8,
                    &sh_w[(g + 1) & 1][tid * 8]);
      bf16x8 afr = *(const bf16x8*)&sh_h1[sidx][r16][ks * 32 + g4 * 8];
      const bf16* wb = &sh_w[g & 1][0];
#pragma unroll
      for (int t = 0; t < 4; ++t) {
        bf16x8 bfr = *(const bf16x8*)(wb + ((hf * 4 + t) * 64 + l) * 8);
        acc[t] = mfma16(afr, bfr, acc[t]);
      }
      if (ks == 3) {
#pragma unroll
        for (int t = 0; t < 4; ++t) {
          float bb = b2[n * 128 + hf * 64 + t * 16 + r16];
#pragma unroll
          for (int j = 0; j < 4; ++j) {
            float v = fmaxf(acc[t][j] + bb, 0.0f);
            sh_h2[sidx][g4 * 4 + j][hf * 64 + t * 16 + r16] = (bf16)v;
          }
        }
      }
      __syncthreads();
      ++g;
    }
    // ---- GEMM3: h2[64x128] x W3[128x128], phases 12..15
#pragma unroll
    for (int t = 0; t < 4; ++t) acc[t] = fz;
#pragma unroll
    for (int ks = 0; ks < 4; ++ks) {
      if (g + 1 < NTASK * 16)
        gload_lds16(chunk_src(g + 1, w1f, w2f, w3f) + (size_t)tid * 8,
                    &sh_w[(g + 1) & 1][tid * 8]);
      bf16x8 afr = *(const bf16x8*)&sh_h2[sidx][r16][ks * 32 + g4 * 8];
      const bf16* wb = &sh_w[g & 1][0];
#pragma unroll
      for (int t = 0; t < 4; ++t) {
        bf16x8 bfr = *(const bf16x8*)(wb + ((hf * 4 + t) * 64 + l) * 8);
        acc[t] = mfma16(afr, bfr, acc[t]);
      }
      if (ks == 2 && tid < 64) sh_norm2[tid] = 0.0f;
      if (ks == 3) {
#pragma unroll
        for (int t = 0; t < 4; ++t) {
          float bb = b3[n * 128 + hf * 64 + t * 16 + r16];
#pragma unroll
          for (int j = 0; j < 4; ++j) acc[t][j] += bb;
        }
      }
      __syncthreads();
      ++g;
    }
    // ---- epilogue for task n: normalize q, cos, latent accum, target ----
#pragma unroll
    for (int j = 0; j < 4; ++j) {
      float ssq = 0.f;
#pragma unroll
      for (int t = 0; t < 4; ++t) ssq += acc[t][j] * acc[t][j];
      ssq += __shfl_xor(ssq, 1); ssq += __shfl_xor(ssq, 2);
      ssq += __shfl_xor(ssq, 4); ssq += __shfl_xor(ssq, 8);
      if (r16 == 0) atomicAdd(&sh_norm2[rloc + j], ssq);
    }
    __syncthreads();
#pragma unroll
    for (int j = 0; j < 4; ++j) {
      float inv = 1.0f / sqrtf(sh_norm2[rloc + j]);
#pragma unroll
      for (int t = 0; t < 4; ++t) acc[t][j] *= inv;
    }
#pragma unroll
    for (int j = 0; j < 4; ++j) {
      float cd = 0.f;
#pragma unroll
      for (int t = 0; t < 4; ++t) cd += acc[t][j] * lgn[t][j];
      cd += __shfl_xor(cd, 1); cd += __shfl_xor(cd, 2);
      cd += __shfl_xor(cd, 4); cd += __shfl_xor(cd, 8);
      if (r16 == 0) atomicAdd(&sh_cs[(rloc + j) * NTASK + n], cd);
      float pw = (float)sh_pp[(rloc + j) * NTASK + n];
#pragma unroll
      for (int t = 0; t < 4; ++t) lat[t][j] += pw * acc[t][j];
      if (sh_tid[rloc + j] == n) {
#pragma unroll
        for (int t = 0; t < 4; ++t)
          out_tgt[(size_t)(row0 + rloc + j) * 128 + hf * 64 + t * 16 + r16] = acc[t][j];
      }
    }
  }
  __syncthreads();  // all cos-sim atomics complete

  // latent_vec + rep_vec[:,256:384]
#pragma unroll
  for (int j = 0; j < 4; ++j) {
    int grow = row0 + rloc + j;
#pragma unroll
    for (int t = 0; t < 4; ++t) {
      int col = hf * 64 + t * 16 + r16;
      out_lat[(size_t)grow * 128 + col] = lat[t][j];
      out_rep[(size_t)grow * 384 + 256 + col] = lat[t][j];
    }
  }
  // log_softmax(cos/0.1): wave w -> rows 8w..8w+7, 8 lanes per row
  {
    int row = w * 8 + (l >> 3);
    int lo = l & 7;
    float v[5];
    float m = -1e30f;
#pragma unroll
    for (int k = 0; k < 5; ++k) {
      int nn = lo + 8 * k;
      v[k] = (nn < NTASK) ? sh_cs[row * NTASK + nn] * 10.0f : -1e30f;
      m = fmaxf(m, v[k]);
    }
    m = fmaxf(m, __shfl_xor(m, 1));
    m = fmaxf(m, __shfl_xor(m, 2));
    m = fmaxf(m, __shfl_xor(m, 4));
    float s = 0.f;
#pragma unroll
    for (int k = 0; k < 5; ++k) {
      int nn = lo + 8 * k;
      if (nn < NTASK) s += expf(v[k] - m);
    }
    s += __shfl_xor(s, 1); s += __shfl_xor(s, 2); s += __shfl_xor(s, 4);
    float lse = logf(s);
#pragma unroll
    for (int k = 0; k < 5; ++k) {
      int nn = lo + 8 * k;
      if (nn < NTASK)
        out_ltp[(size_t)(row0 + row) * NTASK + nn] = v[k] - m - lse;
    }
  }
}

// ---------------- launch ----------------

extern "C" void kernel_launch(void* const* d_in, const int* in_sizes, int n_in,
                              void* d_out, int out_size, void* d_ws, size_t ws_size,
                              hipStream_t stream) {
  (void)in_sizes; (void)n_in; (void)out_size; (void)ws_size;
  const float* state = (const float*)d_in[0];
  const int* task_id = (const int*)d_in[1];
  const float* prior = (const float*)d_in[2];
  const float* W1 = (const float*)d_in[3];
  const float* b1 = (const float*)d_in[4];
  const float* W2 = (const float*)d_in[5];
  const float* b2 = (const float*)d_in[6];
  const float* W3 = (const float*)d_in[7];
  const float* b3 = (const float*)d_in[8];
  const float* lang = (const float*)d_in[9];

  char* ws = (char*)d_ws;
  bf16* w1f = (bf16*)(ws + 0);          // 2,228,224 B
  bf16* w2f = (bf16*)(ws + 2228224);    // 1,114,112 B
  bf16* w3f = (bf16*)(ws + 3342336);    // 1,114,112 B
  bf16* sf = (bf16*)(ws + 4456448);     // 8,388,608 B
  float* langn = (float*)(ws + 12845056);  // 17,408 B
  bf16* pp = (bf16*)(ws + 12862464);    // 1,114,112 B

  float* out = (float*)d_out;
  float* out_rep = out;                 // [B,384]
  float* out_ltp = out + 6291456;       // [B,34]
  float* out_tgt = out + 6848512;       // [B,128]
  float* out_lat = out + 8945664;       // [B,128]

  prep_w<<<544, 256, 0, stream>>>(W1, w1f, 8, 8 * 512, NTASK * 8 * 512);
  prep_w<<<272, 256, 0, stream>>>(W2, w2f, 4, 4 * 512, NTASK * 4 * 512);
  prep_w<<<272, 256, 0, stream>>>(W3, w3f, 4, 4 * 512, NTASK * 4 * 512);
  prep_state_frags<<<2048, 256, 0, stream>>>(state, sf);
  prep_rep<<<16384, 256, 0, stream>>>(state, out_rep);
  prep_langn<<<NTASK, 128, 0, stream>>>(lang, langn);
  prep_pprior<<<4096, 256, 0, stream>>>(prior, pp);
  main_kernel<<<256, 512, 0, stream>>>(task_id, b1, b2, b3, w1f, w2f, w3f, sf,
                                       langn, pp, out_rep, out_ltp, out_tgt, out_lat);
}

// Round 2
// 308.902 us; speedup vs baseline: 1.1159x; 1.1159x over previous
//
#include <hip/hip_runtime.h>
#include <hip/hip_bf16.h>
#include <cstdint>
#include <cstddef>

typedef __bf16 bf16;
typedef __attribute__((ext_vector_type(8))) __bf16 bf16x8;
typedef __attribute__((ext_vector_type(4))) float f32x4;

static_assert(sizeof(bf16x8) == 16, "bf16x8 must be 16B");

#define NTASK 34
#define GTOT (NTASK * 16)   // 544 weight chunks of 8KB

__device__ __forceinline__ f32x4 mfma16(bf16x8 a, bf16x8 b, f32x4 c) {
  return __builtin_amdgcn_mfma_f32_16x16x32_bf16(a, b, c, 0, 0, 0);
}

__device__ __forceinline__ void gload_lds16(const void* g, void* l) {
  __builtin_amdgcn_global_load_lds((__attribute__((address_space(1))) void*)g,
                                   (__attribute__((address_space(3))) void*)l,
                                   16, 0, 0);
}

// end-of-phase: wait chunk(g+1) landed (counted, never 0) + LDS drained, barrier
#define PHASE_END_W(N) do { \
  asm volatile("s_waitcnt vmcnt(" #N ") lgkmcnt(0)" ::: "memory"); \
  __builtin_amdgcn_s_barrier(); \
} while (0)

#define LDS_BARRIER do { \
  asm volatile("s_waitcnt lgkmcnt(0)" ::: "memory"); \
  __builtin_amdgcn_s_barrier(); \
} while (0)

// ---------------- prep kernels ----------------

__global__ void prep_w(const float* __restrict__ src, bf16* __restrict__ dst,
                       int ksteps, int per_n, int total) {
  int idx = blockIdx.x * 256 + threadIdx.x;
  if (idx >= total) return;
  int n = idx / per_n;
  int r = idx - n * per_n;
  int ks = r >> 9;
  int ct = (r >> 6) & 7;
  int l = r & 63;
  int k0 = ks * 32 + ((l >> 4) << 3);
  int col = ct * 16 + (l & 15);
  const float* s = src + ((size_t)n * (ksteps * 32) + k0) * 128 + col;
  bf16x8 v;
#pragma unroll
  for (int j = 0; j < 8; ++j) v[j] = (bf16)s[(size_t)j * 128];
  *(bf16x8*)(dst + (size_t)idx * 8) = v;
}

__global__ void prep_state_frags(const float* __restrict__ state, bf16* __restrict__ dst) {
  int idx = blockIdx.x * 256 + threadIdx.x;   // 524288 total
  int strip = idx >> 9;
  int r = idx & 511;
  int ks = r >> 6;
  int l = r & 63;
  int b = strip * 16 + (l & 15);
  int k0 = ks * 32 + ((l >> 4) << 3);
  const float* s = state + (size_t)b * 256 + k0;
  bf16x8 v;
#pragma unroll
  for (int j = 0; j < 8; ++j) v[j] = (bf16)s[j];
  *(bf16x8*)(dst + (size_t)idx * 8) = v;
}

__global__ void prep_rep(const float* __restrict__ state, float* __restrict__ out_rep) {
  int i = blockIdx.x * 256 + threadIdx.x;
  out_rep[(size_t)(i >> 8) * 384 + (i & 255)] = state[i];
}

__global__ void prep_langn(const float* __restrict__ lang, float* __restrict__ out) {
  __shared__ float red[2];
  int n = blockIdx.x;
  int t = threadIdx.x;
  float v = lang[(size_t)n * 128 + t];
  float ss = v * v;
#pragma unroll
  for (int m = 1; m < 64; m <<= 1) ss += __shfl_xor(ss, m);
  if ((t & 63) == 0) red[t >> 6] = ss;
  __syncthreads();
  float s = red[0] + red[1];
  float sc = 1.0f / fmaxf(sqrtf(s), 1e-8f);
  out[(size_t)n * 128 + t] = v * sc;
}

__global__ void prep_pprior(const float* __restrict__ prior, bf16* __restrict__ pp) {
  int row = blockIdx.x * 4 + (threadIdx.x >> 6);
  int lane = threadIdx.x & 63;
  float v = (lane < NTASK) ? prior[(size_t)row * NTASK + lane] : -INFINITY;
  float m = v;
#pragma unroll
  for (int mm = 1; mm < 64; mm <<= 1) m = fmaxf(m, __shfl_xor(m, mm));
  float e = (lane < NTASK) ? expf(v - m) : 0.0f;
  float s = e;
#pragma unroll
  for (int mm = 1; mm < 64; mm <<= 1) s += __shfl_xor(s, mm);
  if (lane < NTASK) pp[(size_t)row * NTASK + lane] = (bf16)(e / s);
}

// ---------------- main fused kernel ----------------

__device__ __forceinline__ const bf16* chunk_src(int g, const bf16* w1f,
                                                 const bf16* w2f, const bf16* w3f) {
  int n = g >> 4, ph = g & 15;
  if (ph < 8) return w1f + (size_t)(n * 8 + ph) * 4096;
  if (ph < 12) return w2f + (size_t)(n * 4 + (ph - 8)) * 4096;
  return w3f + (size_t)(n * 4 + (ph - 12)) * 4096;
}

__global__ void __launch_bounds__(512, 2)
main_kernel(const int* __restrict__ task_id,
            const float* __restrict__ b1, const float* __restrict__ b2,
            const float* __restrict__ b3,
            const bf16* __restrict__ w1f, const bf16* __restrict__ w2f,
            const bf16* __restrict__ w3f, const bf16* __restrict__ sf,
            const float* __restrict__ langn, const bf16* __restrict__ pp,
            float* __restrict__ out_rep, float* __restrict__ out_ltp,
            float* __restrict__ out_tgt, float* __restrict__ out_lat) {
  __shared__ __align__(16) bf16 sh_w[4][4096];      // 4 x 8KB chunk ring (depth-3)
  __shared__ __align__(16) bf16 sh_h[4][16][136];   // shared h1/h2 (272B row stride)
  __shared__ float sh_cs[64 * NTASK];
  __shared__ bf16 sh_pp[64 * NTASK];
  __shared__ float sh_norm2[64];
  __shared__ int sh_tid[64];
  // total LDS: 32768 + 17408 + 8704 + 4352 + 256 + 256 = 63744 B < 64KB

  const int tid = threadIdx.x;
  const int l = tid & 63;
  const int w = tid >> 6;
  const int sp = w >> 2;        // 0..1: row half (32 rows = strips 2sp, 2sp+1)
  const int cp = w & 3;         // 0..3: col quarter (32 cols)
  const int g4 = l >> 4;
  const int r16 = l & 15;
  const int blk = blockIdx.x;
  const int row0 = blk * 64;
  const int colw = cp * 32 + r16;   // col for t=0; t adds 16

  // prologue: prefetch chunks 0,1,2 (task 0, W1 ks=0..2)
  gload_lds16(w1f + (size_t)tid * 8, &sh_w[0][tid * 8]);
  gload_lds16(w1f + 4096 + (size_t)tid * 8, &sh_w[1][tid * 8]);
  gload_lds16(w1f + 8192 + (size_t)tid * 8, &sh_w[2][tid * 8]);

  if (tid < 64) sh_tid[tid] = task_id[row0 + tid];
  for (int i = tid; i < 64 * NTASK; i += 512) {
    sh_pp[i] = pp[(size_t)row0 * NTASK + i];
    sh_cs[i] = 0.0f;
  }

  // state A-fragments for this wave's 2 strips (registers, reused all tasks)
  bf16x8 sfrag[2][8];
#pragma unroll
  for (int s = 0; s < 2; ++s) {
    const bf16* spp = sf + ((size_t)(blk * 4 + sp * 2 + s) * 8 * 64 + l) * 8;
#pragma unroll
    for (int ks = 0; ks < 8; ++ks)
      sfrag[s][ks] = *(const bf16x8*)(spp + (size_t)ks * 512);
  }

  asm volatile("s_waitcnt vmcnt(2) lgkmcnt(0)" ::: "memory");
  __builtin_amdgcn_s_barrier();

  // per-lane normalized-lang fragment
  float lgn[2][2][4];
#pragma unroll
  for (int s = 0; s < 2; ++s)
#pragma unroll
    for (int j = 0; j < 4; ++j) {
      int trow = sh_tid[sp * 32 + s * 16 + g4 * 4 + j];
#pragma unroll
      for (int t = 0; t < 2; ++t)
        lgn[s][t][j] = langn[(size_t)trow * 128 + colw + t * 16];
    }

  const f32x4 fz = {0.f, 0.f, 0.f, 0.f};
  f32x4 lat[2][2] = {{fz, fz}, {fz, fz}};
  f32x4 acc[2][2] = {{fz, fz}, {fz, fz}};

  // epilogue-2 for task m: acc holds q+b3 of task m
  auto epi2 = [&](int m) {
#pragma unroll
    for (int s = 0; s < 2; ++s)
#pragma unroll
      for (int j = 0; j < 4; ++j) {
        int row = sp * 32 + s * 16 + g4 * 4 + j;
        float inv = 1.0f / sqrtf(sh_norm2[row]);
        float q0 = acc[s][0][j] * inv;
        float q1 = acc[s][1][j] * inv;
        float cd = q0 * lgn[s][0][j] + q1 * lgn[s][1][j];
        cd += __shfl_xor(cd, 1); cd += __shfl_xor(cd, 2);
        cd += __shfl_xor(cd, 4); cd += __shfl_xor(cd, 8);
        if (r16 == 0) atomicAdd(&sh_cs[row * NTASK + m], cd);
        float pw = (float)sh_pp[row * NTASK + m];
        lat[s][0][j] += pw * q0;
        lat[s][1][j] += pw * q1;
        if (sh_tid[row] == m) {
          out_tgt[(size_t)(row0 + row) * 128 + colw] = q0;
          out_tgt[(size_t)(row0 + row) * 128 + colw + 16] = q1;
        }
      }
  };

  int g = 0;
  for (int n = 0; n < NTASK; ++n) {
    // biases for this wave's 2 col-tiles (registers; 6 VMEM loads this phase)
    float b1v[2], b2v[2], b3v[2];
#pragma unroll
    for (int t = 0; t < 2; ++t) {
      b1v[t] = b1[n * 128 + colw + t * 16];
      b2v[t] = b2[n * 128 + colw + t * 16];
      b3v[t] = b3[n * 128 + colw + t * 16];
    }

    if (n > 0) epi2(n - 1);

#pragma unroll
    for (int s = 0; s < 2; ++s)
#pragma unroll
      for (int t = 0; t < 2; ++t) acc[s][t] = fz;

    // ---- GEMM1: state[64x256] x W1 (A in registers), phases ks=0..7
#pragma unroll
    for (int ks = 0; ks < 8; ++ks) {
      int gn = g + 3; if (gn >= GTOT) gn -= GTOT;   // GTOT%4==0 -> slot gn&3 ok
      gload_lds16(chunk_src(gn, w1f, w2f, w3f) + (size_t)tid * 8,
                  &sh_w[gn & 3][tid * 8]);
      const bf16* wb = &sh_w[g & 3][0];
      bf16x8 bf0 = *(const bf16x8*)(wb + ((cp * 2 + 0) * 64 + l) * 8);
      bf16x8 bf1 = *(const bf16x8*)(wb + ((cp * 2 + 1) * 64 + l) * 8);
      acc[0][0] = mfma16(sfrag[0][ks], bf0, acc[0][0]);
      acc[0][1] = mfma16(sfrag[0][ks], bf1, acc[0][1]);
      acc[1][0] = mfma16(sfrag[1][ks], bf0, acc[1][0]);
      acc[1][1] = mfma16(sfrag[1][ks], bf1, acc[1][1]);
      if (ks == 7) {
#pragma unroll
        for (int s = 0; s < 2; ++s)
#pragma unroll
          for (int t = 0; t < 2; ++t)
#pragma unroll
            for (int j = 0; j < 4; ++j) {
              float v = fmaxf(acc[s][t][j] + b1v[t], 0.0f);
              sh_h[sp * 2 + s][g4 * 4 + j][colw + t * 16] = (bf16)v;
            }
      }
      if (ks < 2) { PHASE_END_W(8); } else { PHASE_END_W(2); }
      ++g;
    }

    // ---- GEMM2: h1 x W2, phases ks=0..3
#pragma unroll
    for (int s = 0; s < 2; ++s)
#pragma unroll
      for (int t = 0; t < 2; ++t) acc[s][t] = fz;
    float hv[2][2][4];
#pragma unroll
    for (int ks = 0; ks < 4; ++ks) {
      int gn = g + 3; if (gn >= GTOT) gn -= GTOT;
      gload_lds16(chunk_src(gn, w1f, w2f, w3f) + (size_t)tid * 8,
                  &sh_w[gn & 3][tid * 8]);
      bf16x8 a0 = *(const bf16x8*)&sh_h[sp * 2 + 0][r16][ks * 32 + g4 * 8];
      bf16x8 a1 = *(const bf16x8*)&sh_h[sp * 2 + 1][r16][ks * 32 + g4 * 8];
      const bf16* wb = &sh_w[g & 3][0];
      bf16x8 bf0 = *(const bf16x8*)(wb + ((cp * 2 + 0) * 64 + l) * 8);
      bf16x8 bf1 = *(const bf16x8*)(wb + ((cp * 2 + 1) * 64 + l) * 8);
      acc[0][0] = mfma16(a0, bf0, acc[0][0]);
      acc[0][1] = mfma16(a0, bf1, acc[0][1]);
      acc[1][0] = mfma16(a1, bf0, acc[1][0]);
      acc[1][1] = mfma16(a1, bf1, acc[1][1]);
      if (ks == 3) {
#pragma unroll
        for (int s = 0; s < 2; ++s)
#pragma unroll
          for (int t = 0; t < 2; ++t)
#pragma unroll
            for (int j = 0; j < 4; ++j)
              hv[s][t][j] = fmaxf(acc[s][t][j] + b2v[t], 0.0f);
      }
      PHASE_END_W(2);
      ++g;
    }

    // mini-phase: publish h2 into the shared h buffer
#pragma unroll
    for (int s = 0; s < 2; ++s)
#pragma unroll
      for (int t = 0; t < 2; ++t)
#pragma unroll
        for (int j = 0; j < 4; ++j)
          sh_h[sp * 2 + s][g4 * 4 + j][colw + t * 16] = (bf16)hv[s][t][j];
    LDS_BARRIER;

    // ---- GEMM3: h2 x W3, phases ks=0..3
#pragma unroll
    for (int s = 0; s < 2; ++s)
#pragma unroll
      for (int t = 0; t < 2; ++t) acc[s][t] = fz;
#pragma unroll
    for (int ks = 0; ks < 4; ++ks) {
      int gn = g + 3; if (gn >= GTOT) gn -= GTOT;
      gload_lds16(chunk_src(gn, w1f, w2f, w3f) + (size_t)tid * 8,
                  &sh_w[gn & 3][tid * 8]);
      bf16x8 a0 = *(const bf16x8*)&sh_h[sp * 2 + 0][r16][ks * 32 + g4 * 8];
      bf16x8 a1 = *(const bf16x8*)&sh_h[sp * 2 + 1][r16][ks * 32 + g4 * 8];
      const bf16* wb = &sh_w[g & 3][0];
      bf16x8 bf0 = *(const bf16x8*)(wb + ((cp * 2 + 0) * 64 + l) * 8);
      bf16x8 bf1 = *(const bf16x8*)(wb + ((cp * 2 + 1) * 64 + l) * 8);
      acc[0][0] = mfma16(a0, bf0, acc[0][0]);
      acc[0][1] = mfma16(a0, bf1, acc[0][1]);
      acc[1][0] = mfma16(a1, bf0, acc[1][0]);
      acc[1][1] = mfma16(a1, bf1, acc[1][1]);
      if (ks == 2 && tid < 64) sh_norm2[tid] = 0.0f;
      if (ks == 3) {
#pragma unroll
        for (int s = 0; s < 2; ++s)
#pragma unroll
          for (int t = 0; t < 2; ++t)
#pragma unroll
            for (int j = 0; j < 4; ++j) acc[s][t][j] += b3v[t];
#pragma unroll
        for (int s = 0; s < 2; ++s)
#pragma unroll
          for (int j = 0; j < 4; ++j) {
            float ssq = acc[s][0][j] * acc[s][0][j] + acc[s][1][j] * acc[s][1][j];
            ssq += __shfl_xor(ssq, 1); ssq += __shfl_xor(ssq, 2);
            ssq += __shfl_xor(ssq, 4); ssq += __shfl_xor(ssq, 8);
            if (r16 == 0) atomicAdd(&sh_norm2[sp * 32 + s * 16 + g4 * 4 + j], ssq);
          }
      }
      PHASE_END_W(2);
      ++g;
    }
  }

  epi2(NTASK - 1);

  // latent_vec + rep_vec[:,256:384]
#pragma unroll
  for (int s = 0; s < 2; ++s)
#pragma unroll
    for (int j = 0; j < 4; ++j) {
      int grow = row0 + sp * 32 + s * 16 + g4 * 4 + j;
#pragma unroll
      for (int t = 0; t < 2; ++t) {
        int col = colw + t * 16;
        out_lat[(size_t)grow * 128 + col] = lat[s][t][j];
        out_rep[(size_t)grow * 384 + 256 + col] = lat[s][t][j];
      }
    }

  __syncthreads();   // full drain (incl. tail dummy prefetches) + sh_cs complete

  // log_softmax(cos/0.1): wave w -> rows 8w..8w+7, 8 lanes per row
  {
    int row = w * 8 + (l >> 3);
    int lo = l & 7;
    float v[5];
    float m = -1e30f;
#pragma unroll
    for (int k = 0; k < 5; ++k) {
      int nn = lo + 8 * k;
      v[k] = (nn < NTASK) ? sh_cs[row * NTASK + nn] * 10.0f : -1e30f;
      m = fmaxf(m, v[k]);
    }
    m = fmaxf(m, __shfl_xor(m, 1));
    m = fmaxf(m, __shfl_xor(m, 2));
    m = fmaxf(m, __shfl_xor(m, 4));
    float sum = 0.f;
#pragma unroll
    for (int k = 0; k < 5; ++k) {
      int nn = lo + 8 * k;
      if (nn < NTASK) sum += expf(v[k] - m);
    }
    sum += __shfl_xor(sum, 1); sum += __shfl_xor(sum, 2); sum += __shfl_xor(sum, 4);
    float lse = logf(sum);
#pragma unroll
    for (int k = 0; k < 5; ++k) {
      int nn = lo + 8 * k;
      if (nn < NTASK)
        out_ltp[(size_t)(row0 + row) * NTASK + nn] = v[k] - m - lse;
    }
  }
}

// ---------------- launch ----------------

extern "C" void kernel_launch(void* const* d_in, const int* in_sizes, int n_in,
                              void* d_out, int out_size, void* d_ws, size_t ws_size,
                              hipStream_t stream) {
  (void)in_sizes; (void)n_in; (void)out_size; (void)ws_size;
  const float* state = (const float*)d_in[0];
  const int* task_id = (const int*)d_in[1];
  const float* prior = (const float*)d_in[2];
  const float* W1 = (const float*)d_in[3];
  const float* b1 = (const float*)d_in[4];
  const float* W2 = (const float*)d_in[5];
  const float* b2 = (const float*)d_in[6];
  const float* W3 = (const float*)d_in[7];
  const float* b3 = (const float*)d_in[8];
  const float* lang = (const float*)d_in[9];

  char* ws = (char*)d_ws;
  bf16* w1f = (bf16*)(ws + 0);
  bf16* w2f = (bf16*)(ws + 2228224);
  bf16* w3f = (bf16*)(ws + 3342336);
  bf16* sf = (bf16*)(ws + 4456448);
  float* langn = (float*)(ws + 12845056);
  bf16* pp = (bf16*)(ws + 12862464);

  float* out = (float*)d_out;
  float* out_rep = out;                 // [B,384]
  float* out_ltp = out + 6291456;       // [B,34]
  float* out_tgt = out + 6848512;       // [B,128]
  float* out_lat = out + 8945664;       // [B,128]

  prep_w<<<544, 256, 0, stream>>>(W1, w1f, 8, 8 * 512, NTASK * 8 * 512);
  prep_w<<<272, 256, 0, stream>>>(W2, w2f, 4, 4 * 512, NTASK * 4 * 512);
  prep_w<<<272, 256, 0, stream>>>(W3, w3f, 4, 4 * 512, NTASK * 4 * 512);
  prep_state_frags<<<2048, 256, 0, stream>>>(state, sf);
  prep_rep<<<16384, 256, 0, stream>>>(state, out_rep);
  prep_langn<<<NTASK, 128, 0, stream>>>(lang, langn);
  prep_pprior<<<4096, 256, 0, stream>>>(prior, pp);
  main_kernel<<<256, 512, 0, stream>>>(task_id, b1, b2, b3, w1f, w2f, w3f, sf,
                                       langn, pp, out_rep, out_ltp, out_tgt, out_lat);
}